// Round 5
// baseline (35.520 us; speedup 1.0000x reference)
//
#include <hip/hip_runtime.h>

#define B_SZ   256
#define T_SZ   512
#define EMB    128
#define HID    256
#define NCLS   32000

typedef __attribute__((ext_vector_type(8))) short short8;
typedef __attribute__((ext_vector_type(4))) float f32x4;

__device__ inline unsigned short bf16rne(float f) {
    union { float f; unsigned int u; } v; v.f = f;
    unsigned int u = v.u;
    u += 0x7FFFu + ((u >> 16) & 1u);   // round-to-nearest-even
    return (unsigned short)(u >> 16);
}

__device__ inline unsigned pk2(float lo, float hi) {
    return ((unsigned)bf16rne(hi) << 16) | bf16rne(lo);
}

// ---------------------------------------------------------------------------
// Kernel 1: h_last[b][k] = o0 * tanh(i0 * g0) for the LAST timestep only.
// (layer-0 state never updates; layer-1 scan is discarded; only t = T-1 used)
// UNCHANGED from round 4 (single-variable round: logits only).
// ---------------------------------------------------------------------------
__global__ __launch_bounds__(256)
void lstm_h_last(const int* __restrict__ X, const float* __restrict__ C_table,
                 const float* __restrict__ U_i, const float* __restrict__ b_i,
                 const float* __restrict__ U_c, const float* __restrict__ b_c,
                 const float* __restrict__ U_o, const float* __restrict__ b_o,
                 unsigned short* __restrict__ hws) {
    __shared__ float e[2][EMB];
    __shared__ int idx[2];
    const int t  = threadIdx.x;          // 0..255
    const int b2 = blockIdx.x * 2;

    if (t < 2) idx[t] = X[(size_t)(b2 + t) * T_SZ + (T_SZ - 1)];
    __syncthreads();
    e[t >> 7][t & 127] = C_table[(size_t)idx[t >> 7] * EMB + (t & 127)];
    __syncthreads();

    const int k = t;  // hidden index
    float ai0 = 0.f, ac0 = 0.f, ao0 = 0.f;
    float ai1 = 0.f, ac1 = 0.f, ao1 = 0.f;

    #pragma unroll 8
    for (int ee = 0; ee < EMB; ++ee) {
        float ui = U_i[ee * HID + k];
        float uc = U_c[ee * HID + k];
        float uo = U_o[ee * HID + k];
        float e0 = e[0][ee], e1 = e[1][ee];
        ai0 += e0 * ui; ac0 += e0 * uc; ao0 += e0 * uo;
        ai1 += e1 * ui; ac1 += e1 * uc; ao1 += e1 * uo;
    }

    const float bi = b_i[k], bc = b_c[k], bo = b_o[k];
    {
        float i0 = 1.f / (1.f + expf(-(ai0 + bi)));
        float g0 = tanhf(ac0 + bc);
        float o0 = 1.f / (1.f + expf(-(ao0 + bo)));
        hws[(size_t)b2 * HID + k] = bf16rne(o0 * tanhf(i0 * g0));
    }
    {
        float i0 = 1.f / (1.f + expf(-(ai1 + bi)));
        float g0 = tanhf(ac1 + bc);
        float o0 = 1.f / (1.f + expf(-(ao1 + bo)));
        hws[(size_t)(b2 + 1) * HID + k] = bf16rne(o0 * tanhf(i0 * g0));
    }
}

// ---------------------------------------------------------------------------
// Kernel 2: logits[m][n] = sum_k h[m][k] * W_w[n][k] + b_out[n]
// M=256 N=32000 K=256.
//
// 250 blocks x 512 thr (8 waves), 1 block/CU (96 KB LDS). Wave owns 32
// m-rows (bh[16] = 64 VGPR, pinned with asm keep-alives so the compiler
// cannot sink the loads into the MFMA loop — R2's serial-chain failure).
// Block owns 4 n-tiles of BN=32; W read from HBM exactly once via
// __builtin_amdgcn_global_load_lds width=16 (no VGPR round-trip), fp32 in
// LDS, f32->bf16 cvt on read (VALU ~18% of the 6100cy/tile BW budget).
// Triple-buffered tiles + counted vmcnt (never 0 in the loop) + raw
// s_barrier + sched_barrier(0): loads stay in flight across barriers.
// Swizzle both-sides (rule 21): linear LDS dest, global source float4-idx
// XOR (row&7), read with same XOR -> conflict-free ds_read_b128.
// ---------------------------------------------------------------------------
#define BN  32
#define NT  4

#define WAITB(N) do {                                          \
    asm volatile("s_waitcnt vmcnt(" #N ")" ::: "memory");      \
    __builtin_amdgcn_s_barrier();                              \
    __builtin_amdgcn_sched_barrier(0);                         \
} while (0)

__device__ __forceinline__ void stage_tile(const float* __restrict__ Ww,
                                           int n0, float* buf,
                                           int wid, int lane) {
    // one gload_lds = 64 lanes x 16 B = one full 1 KB row (256 f32)
    #pragma unroll
    for (int i = 0; i < 4; ++i) {
        const int row = wid * 4 + i;                       // wave-uniform
        const float* g = Ww + (size_t)(n0 + row) * HID + ((lane ^ (row & 7)) << 2);
        __builtin_amdgcn_global_load_lds(
            (const __attribute__((address_space(1))) unsigned int*)g,
            (__attribute__((address_space(3))) unsigned int*)(buf + row * HID),
            16, 0, 0);
    }
}

__device__ __forceinline__ void compute_tile(const float* __restrict__ buf,
                                             const short8* __restrict__ bh,
                                             const f32x4* __restrict__ bias2,
                                             float* __restrict__ out,
                                             int ncol_base, int m0,
                                             int l15, int lq) {
    #pragma unroll
    for (int s = 0; s < 2; ++s) {
        const int r  = s * 16 + l15;          // W row for this lane
        const int sw = r & 7;                 // read-side swizzle
        const float* rowp = buf + r * HID;

        short8 aw[8];
        #pragma unroll
        for (int ks = 0; ks < 8; ++ks) {
            const int j0 = ks * 8 + lq * 2;   // float4 index of k-chunk
            f32x4 a0 = *reinterpret_cast<const f32x4*>(rowp + ((j0 ^ sw) << 2));
            f32x4 a1 = *reinterpret_cast<const f32x4*>(rowp + (((j0 + 1) ^ sw) << 2));
            union { short8 v; unsigned u[4]; } p;
            p.u[0] = pk2(a0[0], a0[1]);
            p.u[1] = pk2(a0[2], a0[3]);
            p.u[2] = pk2(a1[0], a1[1]);
            p.u[3] = pk2(a1[2], a1[3]);
            aw[ks] = p.v;
        }

        f32x4 acc[2] = {};
        #pragma unroll
        for (int ks = 0; ks < 8; ++ks)
            #pragma unroll
            for (int mf = 0; mf < 2; ++mf)
                acc[mf] = __builtin_amdgcn_mfma_f32_16x16x32_bf16(
                    aw[ks], bh[mf * 8 + ks], acc[mf], 0, 0, 0);

        // D[n][m]: col = l15 = m, rows = lq*4 + reg = 4 consecutive n
        const int ncol = ncol_base + s * 16 + lq * 4;
        #pragma unroll
        for (int mf = 0; mf < 2; ++mf) {
            f32x4 o = acc[mf] + bias2[s];
            *reinterpret_cast<f32x4*>(
                out + (size_t)(m0 + mf * 16 + l15) * NCLS + ncol) = o;
        }
    }
}

__global__ __launch_bounds__(512, 2)
void logits_gemm(const unsigned short* __restrict__ hws,
                 const float* __restrict__ Ww,
                 const float* __restrict__ b_out,
                 float* __restrict__ out) {
    __shared__ float Bs[3][BN * HID];        // 3 x 32 KB

    const int t    = threadIdx.x;            // 0..511
    const int wid  = t >> 6;                 // 0..7
    const int lane = t & 63;
    const int l15  = lane & 15;
    const int lq   = lane >> 4;              // 0..3

    const int nb = blockIdx.x * (NT * BN);   // 128 n-cols per block
    const int m0 = wid * 32;                 // this wave's m-strip

    // ---- preload h fragments + bias (drained once, before staging) ----
    short8 bh[16];
    #pragma unroll
    for (int mf = 0; mf < 2; ++mf)
        #pragma unroll
        for (int ks = 0; ks < 8; ++ks)
            bh[mf * 8 + ks] = *reinterpret_cast<const short8*>(
                hws + (size_t)(m0 + mf * 16 + l15) * HID + lq * 8 + ks * 32);

    f32x4 bias[8];
    #pragma unroll
    for (int tl = 0; tl < NT; ++tl)
        #pragma unroll
        for (int s = 0; s < 2; ++s)
            bias[tl * 2 + s] = *reinterpret_cast<const f32x4*>(
                b_out + nb + tl * 32 + s * 16 + lq * 4);

    // pin in VGPRs NOW: compiler inserts one vmcnt(0) here instead of
    // sinking 24 loads into the MFMA loop (the R2 serial-chain failure)
    #pragma unroll
    for (int i = 0; i < 16; ++i) asm volatile("" : "+v"(bh[i]));
    #pragma unroll
    for (int i = 0; i < 8; ++i)  asm volatile("" : "+v"(bias[i]));

    // ---- software pipeline over 4 n-tiles, 3 LDS buffers ----
    stage_tile(Ww, nb,          &Bs[0][0], wid, lane);
    stage_tile(Ww, nb + BN,     &Bs[1][0], wid, lane);
    WAITB(4);                                 // tile0 landed (stage1 in flight)

    stage_tile(Ww, nb + 2 * BN, &Bs[2][0], wid, lane);
    compute_tile(&Bs[0][0], bh, &bias[0], out, nb,          m0, l15, lq);
    WAITB(8);                                 // tile1 landed

    stage_tile(Ww, nb + 3 * BN, &Bs[0][0], wid, lane);
    compute_tile(&Bs[1][0], bh, &bias[2], out, nb + BN,     m0, l15, lq);
    WAITB(12);                                // tile2 landed

    compute_tile(&Bs[2][0], bh, &bias[4], out, nb + 2 * BN, m0, l15, lq);
    WAITB(8);                                 // tile3 landed

    compute_tile(&Bs[0][0], bh, &bias[6], out, nb + 3 * BN, m0, l15, lq);
}

// ---------------------------------------------------------------------------
extern "C" void kernel_launch(void* const* d_in, const int* in_sizes, int n_in,
                              void* d_out, int out_size, void* d_ws, size_t ws_size,
                              hipStream_t stream) {
    const int*   X       = (const int*)  d_in[0];
    const float* C_table = (const float*)d_in[1];
    const float* U_i     = (const float*)d_in[2];
    const float* b_i     = (const float*)d_in[4];
    const float* U_c     = (const float*)d_in[8];
    const float* b_c     = (const float*)d_in[10];
    const float* U_o     = (const float*)d_in[11];
    const float* b_o     = (const float*)d_in[13];
    const float* W_w     = (const float*)d_in[26];
    const float* b_out   = (const float*)d_in[27];
    float* out = (float*)d_out;

    unsigned short* hws = (unsigned short*)d_ws;  // bf16 h_last [256][256]

    lstm_h_last<<<B_SZ / 2, 256, 0, stream>>>(X, C_table, U_i, b_i, U_c, b_c,
                                              U_o, b_o, hws);
    logits_gemm<<<NCLS / (NT * BN), 512, 0, stream>>>(hws, W_w, b_out, out);
}

// Round 6
// 30.386 us; speedup vs baseline: 1.1690x; 1.1690x over previous
//
#include <hip/hip_runtime.h>

#define B_SZ   256
#define T_SZ   512
#define EMB    128
#define HID    256
#define NCLS   32000

typedef __attribute__((ext_vector_type(8))) short short8;
typedef __attribute__((ext_vector_type(4))) float f32x4;

__device__ inline unsigned short bf16rne(float f) {
    union { float f; unsigned int u; } v; v.f = f;
    unsigned int u = v.u;
    u += 0x7FFFu + ((u >> 16) & 1u);   // round-to-nearest-even
    return (unsigned short)(u >> 16);
}

// pack two f32 to bf16 pair with round-half-up (cheap: 2 add + and/or/shift)
__device__ inline unsigned pkhi(float lo, float hi) {
    union { float f; unsigned u; } a, b;
    a.f = lo; b.f = hi;
    return ((b.u + 0x8000u) & 0xFFFF0000u) | ((a.u + 0x8000u) >> 16);
}

// ---------------------------------------------------------------------------
// Kernel 1: h_last[b][k] = sigmoid(o)*tanh(sigmoid(i)*tanh(c)) for t = T-1.
// (layer-0 state never updates; layer-1 scan discarded; only last step used)
// 256 blocks (1 batch row each) x 256 thr (thread = hidden k).
// ee-loop in 4 chunks of 32: 96 loads issued, pinned (asm) so the batch
// materializes -> 4 latency waits instead of a 128-long chain.
// ---------------------------------------------------------------------------
__global__ __launch_bounds__(256)
void lstm_h_last(const int* __restrict__ X, const float* __restrict__ C_table,
                 const float* __restrict__ U_i, const float* __restrict__ b_i,
                 const float* __restrict__ U_c, const float* __restrict__ b_c,
                 const float* __restrict__ U_o, const float* __restrict__ b_o,
                 unsigned short* __restrict__ hws) {
    __shared__ float e[EMB];
    const int m = blockIdx.x;
    const int k = threadIdx.x;          // 0..255 = hidden index

    const int token = X[(size_t)m * T_SZ + (T_SZ - 1)];   // uniform -> s_load
    if (k < EMB) e[k] = C_table[(size_t)token * EMB + k];
    __syncthreads();

    float ai = 0.f, ac = 0.f, ao = 0.f;
    #pragma unroll
    for (int c = 0; c < 4; ++c) {
        float ui[32], uc[32], uo[32];
        #pragma unroll
        for (int j = 0; j < 32; ++j) {
            const int ee = c * 32 + j;
            ui[j] = U_i[ee * HID + k];
            uc[j] = U_c[ee * HID + k];
            uo[j] = U_o[ee * HID + k];
        }
        #pragma unroll
        for (int j = 0; j < 32; ++j)
            asm volatile("" : "+v"(ui[j]), "+v"(uc[j]), "+v"(uo[j]));
        #pragma unroll
        for (int j = 0; j < 32; ++j) {
            const float ev = e[c * 32 + j];
            ai += ev * ui[j]; ac += ev * uc[j]; ao += ev * uo[j];
        }
    }

    const float i0 = 1.f / (1.f + expf(-(ai + b_i[k])));
    const float g0 = tanhf(ac + b_c[k]);
    const float o0 = 1.f / (1.f + expf(-(ao + b_o[k])));
    hws[(size_t)m * HID + k] = bf16rne(o0 * tanhf(i0 * g0));
}

// ---------------------------------------------------------------------------
// Kernel 2: logits[m][n] = sum_k h[m][k] * W_w[n][k] + b_out[n]
// M=256 N=32000 K=256.  Canonical k-outer GEMM, BM=256, BN=64, BK=32.
//
// 500 blocks x 512 thr (8 waves), LDS = 3 bufs x (W 8KB + h 16KB) = 72 KB
// -> 2 blocks/CU (barrier stalls covered by the other block, m114).
// Wave = 32 m x 64 n; acc[2][4] = 32 VGPR; total ~90 VGPR -> 16 waves/CU.
// W read from HBM exactly ONCE (33 MB); h (128 KB, L2-resident) streamed
// per block via global_load_lds. 3 gload_lds/wave/K-step (1 W + 2 h),
// uniform across waves; stores ONLY in epilogue -> clean vmcnt counting:
// stage depth-2 ahead, wait vmcnt(3) per step, never 0 until the last.
// LDS XOR-swizzle both-sides (rule 21): inverse swizzle on the per-lane
// GLOBAL source address, linear LDS dest, same XOR on the read side.
// W rows (128 B) would otherwise be a 16-way bank conflict.
// ---------------------------------------------------------------------------
#define BN2 64
#define BK  32

__global__ __launch_bounds__(512, 4)
void logits_gemm(const unsigned short* __restrict__ hws,
                 const float* __restrict__ Ww,
                 const float* __restrict__ b_out,
                 float* __restrict__ out) {
    __shared__ float          Wb[3][BN2 * BK];    // 3 x 8 KB  (f32)
    __shared__ unsigned short Hb[3][B_SZ * BK];   // 3 x 16 KB (bf16)

    const int t    = threadIdx.x;        // 0..511
    const int wid  = t >> 6;             // 0..7
    const int lane = t & 63;
    const int l15  = lane & 15;
    const int lq   = lane >> 4;          // 0..3

    const int n0 = blockIdx.x * BN2;
    const int m0 = wid * 32;             // wave's m-strip

    // ---- staging: 3 global_load_lds per wave per K-step ----
    auto stageW = [&](int ks, float* wb) {
        // LDS rows [wid*8, wid*8+8), lane>>3 = local row (== row&7), lane&7 = 16B unit
        const unsigned gu = (lane & 7) ^ (lane >> 3);        // inverse swizzle
        const float* src = Ww + (size_t)(n0 + (wid << 3) + (lane >> 3)) * HID
                              + ks * BK + gu * 4;
        __builtin_amdgcn_global_load_lds(
            (const __attribute__((address_space(1))) unsigned int*)src,
            (__attribute__((address_space(3))) unsigned int*)(wb + (wid << 3) * BK),
            16, 0, 0);
    };
    auto stageH = [&](int ks, unsigned short* hb) {
        #pragma unroll
        for (int ii = 0; ii < 2; ++ii) {
            const int i = (wid << 1) + ii;                   // 0..15
            // LDS rows [i*16, i*16+16), lane>>2 = local row, lane&3 = 16B unit
            const unsigned gu = (lane & 3) ^ ((lane >> 2) & 3);
            const unsigned short* src = hws + (size_t)((i << 4) + (lane >> 2)) * HID
                                            + ks * BK + gu * 8;
            __builtin_amdgcn_global_load_lds(
                (const __attribute__((address_space(1))) unsigned int*)src,
                (__attribute__((address_space(3))) unsigned int*)(hb + (i << 4) * BK),
                16, 0, 0);
        }
    };

    f32x4 acc[2][4] = {};

    auto computeK = [&](const float* wb, const unsigned short* hb) {
        short8 bh[2];
        #pragma unroll
        for (int mf = 0; mf < 2; ++mf) {
            const int r = m0 + (mf << 4) + l15;
            bh[mf] = *reinterpret_cast<const short8*>(
                hb + r * BK + ((lq ^ (r & 3)) << 3));
        }
        #pragma unroll
        for (int nt = 0; nt < 4; ++nt) {
            const int r  = (nt << 4) + l15;                  // W row
            const int sw = r & 7;
            const float* rp = wb + r * BK;
            f32x4 w0 = *reinterpret_cast<const f32x4*>(rp + ((((lq << 1)    ) ^ sw) << 2));
            f32x4 w1 = *reinterpret_cast<const f32x4*>(rp + ((((lq << 1) | 1) ^ sw) << 2));
            union { short8 s; unsigned u[4]; } p;
            p.u[0] = pkhi(w0[0], w0[1]);
            p.u[1] = pkhi(w0[2], w0[3]);
            p.u[2] = pkhi(w1[0], w1[1]);
            p.u[3] = pkhi(w1[2], w1[3]);
            #pragma unroll
            for (int mf = 0; mf < 2; ++mf)
                acc[mf][nt] = __builtin_amdgcn_mfma_f32_16x16x32_bf16(
                    p.s, bh[mf], acc[mf][nt], 0, 0, 0);
        }
    };

    // ---- prologue: stage K-steps 0 and 1 (6 loads in flight/wave) ----
    stageW(0, Wb[0]); stageH(0, Hb[0]);
    stageW(1, Wb[1]); stageH(1, Hb[1]);

    // ---- main loop: 8 K-steps, 3-buffer rotation, counted vmcnt ----
#define KITER(ks, N) do {                                          \
    asm volatile("s_waitcnt vmcnt(" #N ")" ::: "memory");          \
    __builtin_amdgcn_s_barrier();                                  \
    __builtin_amdgcn_sched_barrier(0);                             \
    if ((ks) + 2 < 8) {                                            \
        stageW((ks) + 2, Wb[((ks) + 2) % 3]);                      \
        stageH((ks) + 2, Hb[((ks) + 2) % 3]);                      \
    }                                                              \
    computeK(Wb[(ks) % 3], Hb[(ks) % 3]);                          \
} while (0)

    KITER(0, 3); KITER(1, 3); KITER(2, 3); KITER(3, 3);
    KITER(4, 3); KITER(5, 3); KITER(6, 3); KITER(7, 0);
#undef KITER

    // ---- epilogue: bias + float4 stores (D[n][m]: col=l15=m, 4 consec n) ----
    #pragma unroll
    for (int nt = 0; nt < 4; ++nt) {
        const int nc = n0 + (nt << 4) + (lq << 2);
        f32x4 bv = *reinterpret_cast<const f32x4*>(b_out + nc);
        #pragma unroll
        for (int mf = 0; mf < 2; ++mf) {
            f32x4 o = acc[mf][nt] + bv;
            *reinterpret_cast<f32x4*>(
                out + (size_t)(m0 + (mf << 4) + l15) * NCLS + nc) = o;
        }
    }
}

// ---------------------------------------------------------------------------
extern "C" void kernel_launch(void* const* d_in, const int* in_sizes, int n_in,
                              void* d_out, int out_size, void* d_ws, size_t ws_size,
                              hipStream_t stream) {
    const int*   X       = (const int*)  d_in[0];
    const float* C_table = (const float*)d_in[1];
    const float* U_i     = (const float*)d_in[2];
    const float* b_i     = (const float*)d_in[4];
    const float* U_c     = (const float*)d_in[8];
    const float* b_c     = (const float*)d_in[10];
    const float* U_o     = (const float*)d_in[11];
    const float* b_o     = (const float*)d_in[13];
    const float* W_w     = (const float*)d_in[26];
    const float* b_out   = (const float*)d_in[27];
    float* out = (float*)d_out;

    unsigned short* hws = (unsigned short*)d_ws;  // bf16 h_last [256][256]

    lstm_h_last<<<B_SZ, 256, 0, stream>>>(X, C_table, U_i, b_i, U_c, b_c,
                                          U_o, b_o, hws);
    logits_gemm<<<NCLS / BN2, 512, 0, stream>>>(hws, W_w, b_out, out);
}

// Round 7
// 30.142 us; speedup vs baseline: 1.1784x; 1.0081x over previous
//
#include <hip/hip_runtime.h>

#define B_SZ   256
#define T_SZ   512
#define EMB    128
#define HID    256
#define NCLS   32000

typedef __attribute__((ext_vector_type(8))) short short8;
typedef __attribute__((ext_vector_type(4))) float f32x4;

__device__ inline unsigned short bf16rne(float f) {
    union { float f; unsigned int u; } v; v.f = f;
    unsigned int u = v.u;
    u += 0x7FFFu + ((u >> 16) & 1u);   // round-to-nearest-even
    return (unsigned short)(u >> 16);
}

// pack two f32 to bf16 pair (round-half-up, matches R1-R6 passing absmax)
__device__ inline unsigned pkhi(float lo, float hi) {
    union { float f; unsigned u; } a, b;
    a.f = lo; b.f = hi;
    return ((b.u + 0x8000u) & 0xFFFF0000u) | ((a.u + 0x8000u) >> 16);
}

// ---------------------------------------------------------------------------
// h is stored FRAG-MAJOR in d_ws: element (m,k) lives at
//   frag_id = (m>>4)*8 + (k>>5)            (mf*8 + ks)
//   lane    = ((k>>3)&3)*16 + (m&15)       (lq*16 + l15)
//   idx     = frag_id*512 + lane*8 + (k&7)
// so logits' B-fragment (mf,ks) is a contiguous 1 KB block, lane-linear:
// LDS staging needs no swizzle and ds_read_b128 is conflict-free.
// ---------------------------------------------------------------------------

// ---------------------------------------------------------------------------
// Kernel 1: h_last[b][k] = sigmoid(o)*tanh(sigmoid(i)*tanh(c)) for t = T-1.
// (layer-0 state never updates; layer-1 scan discarded; only last step used)
// 256 blocks (1 batch row) x 256 thr (thread = hidden k); 4 chunks of 32
// with pinned load batches. Stores to the frag-major layout above.
// ---------------------------------------------------------------------------
__global__ __launch_bounds__(256)
void lstm_h_last(const int* __restrict__ X, const float* __restrict__ C_table,
                 const float* __restrict__ U_i, const float* __restrict__ b_i,
                 const float* __restrict__ U_c, const float* __restrict__ b_c,
                 const float* __restrict__ U_o, const float* __restrict__ b_o,
                 unsigned short* __restrict__ hws) {
    __shared__ float e[EMB];
    const int m = blockIdx.x;
    const int k = threadIdx.x;          // 0..255 = hidden index

    const int token = X[(size_t)m * T_SZ + (T_SZ - 1)];   // uniform
    if (k < EMB) e[k] = C_table[(size_t)token * EMB + k];
    __syncthreads();

    float ai = 0.f, ac = 0.f, ao = 0.f;
    #pragma unroll
    for (int c = 0; c < 4; ++c) {
        float ui[32], uc[32], uo[32];
        #pragma unroll
        for (int j = 0; j < 32; ++j) {
            const int ee = c * 32 + j;
            ui[j] = U_i[ee * HID + k];
            uc[j] = U_c[ee * HID + k];
            uo[j] = U_o[ee * HID + k];
        }
        #pragma unroll
        for (int j = 0; j < 32; ++j)
            asm volatile("" : "+v"(ui[j]), "+v"(uc[j]), "+v"(uo[j]));
        #pragma unroll
        for (int j = 0; j < 32; ++j) {
            const float ev = e[c * 32 + j];
            ai += ev * ui[j]; ac += ev * uc[j]; ao += ev * uo[j];
        }
    }

    const float i0 = 1.f / (1.f + expf(-(ai + b_i[k])));
    const float g0 = tanhf(ac + b_c[k]);
    const float o0 = 1.f / (1.f + expf(-(ao + b_o[k])));
    const unsigned short hv = bf16rne(o0 * tanhf(i0 * g0));

    const int frag_id = (m >> 4) * 8 + (k >> 5);
    const int lane_in = ((k >> 3) & 3) * 16 + (m & 15);
    hws[frag_id * 512 + lane_in * 8 + (k & 7)] = hv;
}

// ---------------------------------------------------------------------------
// Kernel 2: logits[m][n] = sum_k h[m][k] * W_w[n][k] + b_out[n]
// M=256 N=32000 K=256.  ONE-SHOT streaming GEMM: no K-loop, one barrier.
//
// 250 blocks x 512 thr (8 waves, 128 KB LDS -> 1 block/CU, all resident).
// Wave owns a 16-n stripe x all 256 m:
//   1. issue 16 W float4 loads (full K stripe, HBM starts immediately)
//   2. issue 16 global_load_lds staging this wave's 16 KB slice of
//      frag-major h (LINEAR dest, LINEAR source - no swizzle, rule 21)
//   3. pin W, one vmcnt(0) + s_barrier (only barrier in the kernel)
//   4. cvt W->bf16, then ks-outer MFMA: 8 ks x 16 mf, B-frags via
//      conflict-free ds_read_b128 (uniform base + lane*16)
//   5. bias + 16 float4 stores (D: col=l15=m, rows=lq*4+reg=4 consec n)
// W read from HBM exactly once (33 MB); writes 33 MB; h from L2.
// Chip-wide ~32 MB of reads in flight at t=0 -> HBM saturated.
// ---------------------------------------------------------------------------
__global__ __launch_bounds__(512, 2)
void logits_gemm(const unsigned short* __restrict__ hws,
                 const float* __restrict__ Ww,
                 const float* __restrict__ b_out,
                 float* __restrict__ out) {
    __shared__ unsigned short Hs[B_SZ * HID];   // 128 KB, frag-major linear

    const int t    = threadIdx.x;        // 0..511
    const int wid  = t >> 6;             // 0..7
    const int lane = t & 63;
    const int l15  = lane & 15;
    const int lq   = lane >> 4;          // 0..3

    const int nbase = blockIdx.x * 128 + wid * 16;

    // ---- 1. W loads: full K=256 stripe for this lane's n-row ----
    const float* wrow = Ww + (size_t)(nbase + l15) * HID + lq * 8;
    f32x4 wf[16];
    #pragma unroll
    for (int ks = 0; ks < 8; ++ks) {
        wf[2 * ks]     = *reinterpret_cast<const f32x4*>(wrow + ks * 32);
        wf[2 * ks + 1] = *reinterpret_cast<const f32x4*>(wrow + ks * 32 + 4);
    }

    // ---- 2. stage h slice [wid*16KB, +16KB): 16 x 1KB, fully linear ----
    #pragma unroll
    for (int j = 0; j < 16; ++j) {
        const unsigned short* src = hws + (wid * 16 + j) * 512;
        __builtin_amdgcn_global_load_lds(
            (const __attribute__((address_space(1))) unsigned int*)(src + lane * 8),
            (__attribute__((address_space(3))) unsigned int*)(Hs + (wid * 16 + j) * 512),
            16, 0, 0);
    }

    // ---- 3. pin W (forces materialization), drain, barrier ----
    #pragma unroll
    for (int i = 0; i < 16; ++i) asm volatile("" : "+v"(wf[i]));
    asm volatile("s_waitcnt vmcnt(0)" ::: "memory");
    __builtin_amdgcn_s_barrier();
    __builtin_amdgcn_sched_barrier(0);

    // ---- 4. convert W to bf16 A-fragments ----
    short8 aw[8];
    #pragma unroll
    for (int ks = 0; ks < 8; ++ks) {
        union { short8 s; unsigned u[4]; } p;
        p.u[0] = pkhi(wf[2 * ks][0],     wf[2 * ks][1]);
        p.u[1] = pkhi(wf[2 * ks][2],     wf[2 * ks][3]);
        p.u[2] = pkhi(wf[2 * ks + 1][0], wf[2 * ks + 1][1]);
        p.u[3] = pkhi(wf[2 * ks + 1][2], wf[2 * ks + 1][3]);
        aw[ks] = p.s;
    }

    f32x4 bv = *reinterpret_cast<const f32x4*>(b_out + nbase + lq * 4);

    // ---- MFMA: ks-outer -> 16 independent acc chains ----
    const unsigned short* hbase = Hs + lane * 8;
    f32x4 acc[16] = {};
    #pragma unroll
    for (int ks = 0; ks < 8; ++ks) {
        #pragma unroll
        for (int mf = 0; mf < 16; ++mf) {
            short8 bh = *reinterpret_cast<const short8*>(
                hbase + (mf * 8 + ks) * 512);
            acc[mf] = __builtin_amdgcn_mfma_f32_16x16x32_bf16(
                aw[ks], bh, acc[mf], 0, 0, 0);
        }
    }

    // ---- 5. epilogue: bias + stores ----
    #pragma unroll
    for (int mf = 0; mf < 16; ++mf) {
        f32x4 o = acc[mf] + bv;
        *reinterpret_cast<f32x4*>(
            out + (size_t)(mf * 16 + l15) * NCLS + nbase + lq * 4) = o;
    }
}

// ---------------------------------------------------------------------------
extern "C" void kernel_launch(void* const* d_in, const int* in_sizes, int n_in,
                              void* d_out, int out_size, void* d_ws, size_t ws_size,
                              hipStream_t stream) {
    const int*   X       = (const int*)  d_in[0];
    const float* C_table = (const float*)d_in[1];
    const float* U_i     = (const float*)d_in[2];
    const float* b_i     = (const float*)d_in[4];
    const float* U_c     = (const float*)d_in[8];
    const float* b_c     = (const float*)d_in[10];
    const float* U_o     = (const float*)d_in[11];
    const float* b_o     = (const float*)d_in[13];
    const float* W_w     = (const float*)d_in[26];
    const float* b_out   = (const float*)d_in[27];
    float* out = (float*)d_out;

    unsigned short* hws = (unsigned short*)d_ws;  // bf16 h_last, frag-major

    lstm_h_last<<<B_SZ, 256, 0, stream>>>(X, C_table, U_i, b_i, U_c, b_c,
                                          U_o, b_o, hws);
    logits_gemm<<<NCLS / 128, 512, 0, stream>>>(hws, W_w, b_out, out);
}